// Round 2
// baseline (243.817 us; speedup 1.0000x reference)
//
#include <hip/hip_runtime.h>
#include <hip/hip_bf16.h>

#define B_ 2
#define S_ 2048
#define D_ 1024
#define H_ 16
#define DEPTH_ 64

typedef __attribute__((ext_vector_type(4))) float f32x4;
typedef __attribute__((ext_vector_type(8))) short bf16x8;
typedef const __attribute__((address_space(1))) unsigned int gu32;
typedef __attribute__((address_space(3))) unsigned int lu32;

__device__ __forceinline__ void gload_lds16(const void* g, void* l) {
  __builtin_amdgcn_global_load_lds((gu32*)g, (lu32*)l, 16, 0, 0);
}

__device__ __forceinline__ short f2bf(float f) {
  union { float f; unsigned u; } v; v.f = f;
  return (short)((v.u + 0x7FFFu + ((v.u >> 16) & 1u)) >> 16);
}

// ---------- cast fp32 -> bf16 (4 elems/thread) ----------
__global__ __launch_bounds__(256) void cast_kernel(const float* __restrict__ in,
                                                   short* __restrict__ out, int n4) {
  int i = blockIdx.x * 256 + threadIdx.x;
  if (i < n4) {
    const float4 v = reinterpret_cast<const float4*>(in)[i];
    short4 o;
    o.x = f2bf(v.x); o.y = f2bf(v.y); o.z = f2bf(v.z); o.w = f2bf(v.w);
    reinterpret_cast<short4*>(out)[i] = o;
  }
}

// ---------- transpose + cast: W[K][N] f32 -> WT[N][K] bf16 ----------
__global__ __launch_bounds__(256) void transpose_cast_kernel(const float* __restrict__ W,
                                                             short* __restrict__ WT,
                                                             int K, int N) {
  __shared__ short tile[32][33];
  int n0 = blockIdx.x * 32, k0 = blockIdx.y * 32;
  int tx = threadIdx.x, ty = threadIdx.y;
#pragma unroll
  for (int j = 0; j < 4; ++j)
    tile[ty + 8 * j][tx] = f2bf(W[(size_t)(k0 + ty + 8 * j) * N + n0 + tx]);
  __syncthreads();
#pragma unroll
  for (int j = 0; j < 4; ++j)
    WT[(size_t)(n0 + ty + 8 * j) * K + k0 + tx] = tile[tx][ty + 8 * j];
}

// ---------- GEMM (m97 structure): C = A[M][K] * BT[N][K]^T + bias ----------
// linear LDS [128][64], global_load_lds width=16
// EPI 0: scatter bf16 into Qh/Kh (head-split) and VT (transposed V)
// EPI 1: fp32 output to Out[M][N]
template <int EPI>
__global__ __launch_bounds__(256) void gemm_bt_kernel(
    const short* __restrict__ A, const short* __restrict__ BT,
    const float* __restrict__ bias,
    short* __restrict__ Qh, short* __restrict__ Kh, short* __restrict__ VTt,
    float* __restrict__ Out, int M, int N, int K) {
  __shared__ short As[128 * 64];
  __shared__ short Bs[128 * 64];
  const int bm = blockIdx.y * 128, bn = blockIdx.x * 128;
  const int tid = threadIdx.x;
  const int wave = tid >> 6, lane = tid & 63;
  const int wr = wave >> 1, wc = wave & 1;      // 2x2 wave grid, 64x64 each
  const int lr = lane & 15, lg = lane >> 4;
  const int srow = wave * 32 + (lane >> 3);     // staging row (+i*8)
  const int scol = (lane & 7) * 8;              // staging col (shorts)
  f32x4 acc[4][4] = {};
  const int nk = K >> 6;
  for (int kt = 0; kt < nk; ++kt) {
    __syncthreads();
    const short* pa = &A[(size_t)(bm + srow) * K + kt * 64 + scol];
    const short* pb = &BT[(size_t)(bn + srow) * K + kt * 64 + scol];
#pragma unroll
    for (int i = 0; i < 4; ++i) {
      gload_lds16(pa + (size_t)(i * 8) * K, &As[(wave * 32 + i * 8) * 64]);
      gload_lds16(pb + (size_t)(i * 8) * K, &Bs[(wave * 32 + i * 8) * 64]);
    }
    __syncthreads();
#pragma unroll
    for (int ks = 0; ks < 2; ++ks) {
      bf16x8 af[4], bfr[4];
#pragma unroll
      for (int mi = 0; mi < 4; ++mi)
        af[mi] = *reinterpret_cast<const bf16x8*>(&As[(64 * wr + 16 * mi + lr) * 64 + 8 * lg + 32 * ks]);
#pragma unroll
      for (int ni = 0; ni < 4; ++ni)
        bfr[ni] = *reinterpret_cast<const bf16x8*>(&Bs[(64 * wc + 16 * ni + lr) * 64 + 8 * lg + 32 * ks]);
#pragma unroll
      for (int mi = 0; mi < 4; ++mi)
#pragma unroll
        for (int ni = 0; ni < 4; ++ni)
          acc[mi][ni] = __builtin_amdgcn_mfma_f32_16x16x32_bf16(af[mi], bfr[ni], acc[mi][ni], 0, 0, 0);
    }
  }
  // epilogue: D layout col = lane&15, row = 4*(lane>>4)+r  [m89 verified]
#pragma unroll
  for (int mi = 0; mi < 4; ++mi) {
#pragma unroll
    for (int ni = 0; ni < 4; ++ni) {
#pragma unroll
      for (int r = 0; r < 4; ++r) {
        int row = bm + 64 * wr + 16 * mi + 4 * lg + r;
        int col = bn + 64 * wc + 16 * ni + lr;
        float v = acc[mi][ni][r] + bias[col];
        if (EPI == 0) {
          int b = row >> 11, s = row & (S_ - 1);
          int which = col >> 10, cm = col & (D_ - 1);
          int h = cm >> 6, dd = cm & 63;
          short bv = f2bf(v);
          size_t bh = (size_t)(b * H_ + h);
          if (which == 0)      Qh[(bh * S_ + s) * DEPTH_ + dd] = bv;
          else if (which == 1) Kh[(bh * S_ + s) * DEPTH_ + dd] = bv;
          else                 VTt[(bh * DEPTH_ + dd) * S_ + s] = bv;
        } else {
          Out[(size_t)row * N + col] = v;
        }
      }
    }
  }
}

// ---------- flash attention: 1 block per (b,h,qtile of 64), KVBLK=128 ----------
__global__ __launch_bounds__(256) void attn_kernel(
    const short* __restrict__ Qh, const short* __restrict__ Kh,
    const short* __restrict__ VTt, const float* __restrict__ mask,
    short* __restrict__ ctx) {
  constexpr int LKK = 72;    // K rows: 64 + 8 pad
  constexpr int LKV = 136;   // V^T / Ps rows: 128 + 8 pad
  constexpr float LOG2E = 1.44269504f;
  __shared__ short Ks[128 * LKK];      // [kv][d]
  __shared__ short Vs[64 * LKV];       // [d][kv]  (V^T)
  __shared__ short Ps[4][16 * LKV];    // per-wave P strip [q][kv]
  const int bid = blockIdx.x;
  const int qt = 31 - (bid & 31);      // heavy-first (LPT) remap
  const int bh = bid >> 5;
  const int b = bh >> 4, h = bh & 15;
  const short* Qp = Qh + (size_t)bh * S_ * DEPTH_;
  const short* Kp = Kh + (size_t)bh * S_ * DEPTH_;
  const short* Vp = VTt + (size_t)bh * DEPTH_ * S_;
  const int q0 = qt * 64;
  const int tid = threadIdx.x;
  const int wave = tid >> 6, lane = tid & 63;
  const int lr = lane & 15, lg = lane >> 4;

  // Q fragments in registers (wave owns q rows [q0+16*wave, +16))
  bf16x8 qf[2];
  {
    int qrow = q0 + 16 * wave + lr;
    qf[0] = *reinterpret_cast<const bf16x8*>(&Qp[(size_t)qrow * DEPTH_ + 8 * lg]);
    qf[1] = *reinterpret_cast<const bf16x8*>(&Qp[(size_t)qrow * DEPTH_ + 32 + 8 * lg]);
  }
  float m_run[4], l_run[4];
  f32x4 acc_o[4] = {};
#pragma unroll
  for (int r = 0; r < 4; ++r) { m_run[r] = -1e30f; l_run[r] = 0.f; }

  const int nt = (qt + 2) >> 1;  // causal: kv tiles of 128 covering q0+63
  for (int kt = 0; kt < nt; ++kt) {
    const int k0 = kt * 128;
    __syncthreads();
    // stage K[128][64] and V^T[64][128] (reg round-trip, padded LDS)
    {
      bf16x8 tk[4], tv[4];
#pragma unroll
      for (int i = 0; i < 4; ++i) {
        int slot = tid + 256 * i;            // 1024: 128 rows x 8 cgs
        int row = slot >> 3, cg = slot & 7;
        tk[i] = *reinterpret_cast<const bf16x8*>(&Kp[(size_t)(k0 + row) * DEPTH_ + cg * 8]);
        int slot2 = tid + 256 * i;           // 1024: 64 rows x 16 cgs
        int vrow = slot2 >> 4, vcg = slot2 & 15;
        tv[i] = *reinterpret_cast<const bf16x8*>(&Vp[(size_t)vrow * S_ + k0 + vcg * 8]);
      }
#pragma unroll
      for (int i = 0; i < 4; ++i) {
        int slot = tid + 256 * i;
        int row = slot >> 3, cg = slot & 7;
        *reinterpret_cast<bf16x8*>(&Ks[row * LKK + cg * 8]) = tk[i];
        int vrow = slot >> 4, vcg = slot & 15;
        *reinterpret_cast<bf16x8*>(&Vs[vrow * LKV + vcg * 8]) = tv[i];
      }
    }
    __syncthreads();

    // S = Q K^T : sc[f] holds q=4*lg+r (strip-local), kv=k0+16*f+lr
    f32x4 sc[8];
#pragma unroll
    for (int f = 0; f < 8; ++f) { f32x4 z = {0.f, 0.f, 0.f, 0.f}; sc[f] = z; }
#pragma unroll
    for (int ks = 0; ks < 2; ++ks) {
#pragma unroll
      for (int f = 0; f < 8; ++f) {
        bf16x8 kf = *reinterpret_cast<const bf16x8*>(&Ks[(16 * f + lr) * LKK + 8 * lg + 32 * ks]);
        sc[f] = __builtin_amdgcn_mfma_f32_16x16x32_bf16(qf[ks], kf, sc[f], 0, 0, 0);
      }
    }
    // scale (log2 domain) + additive mask + causal (diagonal tile only)
    constexpr float SC = 0.125f * LOG2E;
#pragma unroll
    for (int f = 0; f < 8; ++f) {
      float mv = mask[(size_t)b * S_ + k0 + 16 * f + lr] * LOG2E;
#pragma unroll
      for (int r = 0; r < 4; ++r) {
        float s = sc[f][r] * SC + mv;
        if (kt == nt - 1) {
          int qg = q0 + 16 * wave + 4 * lg + r;
          int kg = k0 + 16 * f + lr;
          if (kg > qg) s -= 2e9f;
        }
        sc[f][r] = s;
      }
    }
    // online softmax (row reduce across 8 frags + 16-lane butterfly)
#pragma unroll
    for (int r = 0; r < 4; ++r) {
      float m = fmaxf(fmaxf(fmaxf(sc[0][r], sc[1][r]), fmaxf(sc[2][r], sc[3][r])),
                      fmaxf(fmaxf(sc[4][r], sc[5][r]), fmaxf(sc[6][r], sc[7][r])));
#pragma unroll
      for (int off = 1; off < 16; off <<= 1) m = fmaxf(m, __shfl_xor(m, off));
      float m_new = fmaxf(m_run[r], m);
      float corr = exp2f(m_run[r] - m_new);
      float su = 0.f;
#pragma unroll
      for (int f = 0; f < 8; ++f) {
        float p = exp2f(sc[f][r] - m_new);
        sc[f][r] = p;
        su += p;
      }
#pragma unroll
      for (int off = 1; off < 16; off <<= 1) su += __shfl_xor(su, off);
      l_run[r] = l_run[r] * corr + su;
      m_run[r] = m_new;
#pragma unroll
      for (int df = 0; df < 4; ++df) acc_o[df][r] *= corr;
    }
    // P -> wave-private LDS strip (no barrier needed: same-wave write/read)
#pragma unroll
    for (int f = 0; f < 8; ++f)
#pragma unroll
      for (int r = 0; r < 4; ++r)
        Ps[wave][(4 * lg + r) * LKV + 16 * f + lr] = f2bf(sc[f][r]);
    // ctx += P V
#pragma unroll
    for (int ks = 0; ks < 4; ++ks) {
      bf16x8 ap = *reinterpret_cast<const bf16x8*>(&Ps[wave][lr * LKV + 8 * lg + 32 * ks]);
#pragma unroll
      for (int df = 0; df < 4; ++df) {
        bf16x8 bv = *reinterpret_cast<const bf16x8*>(&Vs[(16 * df + lr) * LKV + 8 * lg + 32 * ks]);
        acc_o[df] = __builtin_amdgcn_mfma_f32_16x16x32_bf16(ap, bv, acc_o[df], 0, 0, 0);
      }
    }
  }
  // epilogue: ctx[b][q][h*64+d] bf16 (merged-head layout for out-proj)
#pragma unroll
  for (int df = 0; df < 4; ++df) {
#pragma unroll
    for (int r = 0; r < 4; ++r) {
      int q = q0 + 16 * wave + 4 * lg + r;
      int col = h * 64 + 16 * df + lr;
      float v = acc_o[df][r] / l_run[r];
      ctx[((size_t)b * S_ + q) * D_ + col] = f2bf(v);
    }
  }
}

extern "C" void kernel_launch(void* const* d_in, const int* in_sizes, int n_in,
                              void* d_out, int out_size, void* d_ws, size_t ws_size,
                              hipStream_t stream) {
  const float* X    = (const float*)d_in[0];
  const float* mask = (const float*)d_in[1];
  const float* Wqkv = (const float*)d_in[2];
  const float* bqkv = (const float*)d_in[3];
  const float* Wout = (const float*)d_in[4];
  const float* bout = (const float*)d_in[5];
  float* Out = (float*)d_out;

  short* ws    = (short*)d_ws;
  short* Xb    = ws;                                   // 4096*1024 bf16
  short* WqkvT = Xb + (size_t)4096 * 1024;             // [3072][1024]
  short* WoutT = WqkvT + (size_t)3072 * 1024;          // [1024][1024]
  short* Qh    = WoutT + (size_t)1024 * 1024;          // [bh][s][64]
  short* Kh    = Qh + (size_t)B_ * H_ * S_ * DEPTH_;   // [bh][s][64]
  short* VTt   = Kh + (size_t)B_ * H_ * S_ * DEPTH_;   // [bh][64][s]
  short* ctx   = VTt + (size_t)B_ * H_ * S_ * DEPTH_;  // [b][s][1024]

  cast_kernel<<<4096, 256, 0, stream>>>(X, Xb, (4096 * 1024) / 4);
  transpose_cast_kernel<<<dim3(96, 32), dim3(32, 8), 0, stream>>>(Wqkv, WqkvT, 1024, 3072);
  transpose_cast_kernel<<<dim3(32, 32), dim3(32, 8), 0, stream>>>(Wout, WoutT, 1024, 1024);
  gemm_bt_kernel<0><<<dim3(24, 32), 256, 0, stream>>>(Xb, WqkvT, bqkv, Qh, Kh, VTt, nullptr,
                                                      4096, 3072, 1024);
  attn_kernel<<<1024, 256, 0, stream>>>(Qh, Kh, VTt, mask, ctx);
  gemm_bt_kernel<1><<<dim3(8, 32), 256, 0, stream>>>(ctx, WoutT, bout, nullptr, nullptr, nullptr,
                                                     Out, 4096, 1024, 1024);
}

// Round 3
// 195.166 us; speedup vs baseline: 1.2493x; 1.2493x over previous
//
#include <hip/hip_runtime.h>
#include <hip/hip_bf16.h>

#define B_ 2
#define S_ 2048
#define D_ 1024
#define H_ 16
#define DEPTH_ 64

typedef __attribute__((ext_vector_type(4))) float f32x4;
typedef __attribute__((ext_vector_type(8))) short bf16x8;
typedef const __attribute__((address_space(1))) unsigned int gu32;
typedef __attribute__((address_space(3))) unsigned int lu32;

__device__ __forceinline__ void gload_lds16(const void* g, void* l) {
  __builtin_amdgcn_global_load_lds((gu32*)g, (lu32*)l, 16, 0, 0);
}

__device__ __forceinline__ short f2bf(float f) {
  union { float f; unsigned u; } v; v.f = f;
  return (short)((v.u + 0x7FFFu + ((v.u >> 16) & 1u)) >> 16);
}

// ---------- cast fp32 -> bf16 (4 elems/thread) ----------
__global__ __launch_bounds__(256) void cast_kernel(const float* __restrict__ in,
                                                   short* __restrict__ out, int n4) {
  int i = blockIdx.x * 256 + threadIdx.x;
  if (i < n4) {
    const float4 v = reinterpret_cast<const float4*>(in)[i];
    short4 o;
    o.x = f2bf(v.x); o.y = f2bf(v.y); o.z = f2bf(v.z); o.w = f2bf(v.w);
    reinterpret_cast<short4*>(out)[i] = o;
  }
}

// ---------- transpose + cast: W[K][N] f32 -> WT[N][K] bf16 ----------
__global__ __launch_bounds__(256) void transpose_cast_kernel(const float* __restrict__ W,
                                                             short* __restrict__ WT,
                                                             int K, int N) {
  __shared__ short tile[32][33];
  int n0 = blockIdx.x * 32, k0 = blockIdx.y * 32;
  int tx = threadIdx.x, ty = threadIdx.y;
#pragma unroll
  for (int j = 0; j < 4; ++j)
    tile[ty + 8 * j][tx] = f2bf(W[(size_t)(k0 + ty + 8 * j) * N + n0 + tx]);
  __syncthreads();
#pragma unroll
  for (int j = 0; j < 4; ++j)
    WT[(size_t)(n0 + ty + 8 * j) * K + k0 + tx] = tile[tx][ty + 8 * j];
}

// ---------- GEMM (m97 structure): C = A[M][K] * BT[N][K]^T + bias ----------
template <int EPI>
__global__ __launch_bounds__(256) void gemm_bt_kernel(
    const short* __restrict__ A, const short* __restrict__ BT,
    const float* __restrict__ bias,
    short* __restrict__ Qh, short* __restrict__ Kh, short* __restrict__ VTt,
    float* __restrict__ Out, int M, int N, int K) {
  __shared__ short As[128 * 64];
  __shared__ short Bs[128 * 64];
  const int bm = blockIdx.y * 128, bn = blockIdx.x * 128;
  const int tid = threadIdx.x;
  const int wave = tid >> 6, lane = tid & 63;
  const int wr = wave >> 1, wc = wave & 1;      // 2x2 wave grid, 64x64 each
  const int lr = lane & 15, lg = lane >> 4;
  const int srow = wave * 32 + (lane >> 3);     // staging row (+i*8)
  const int scol = (lane & 7) * 8;              // staging col (shorts)
  f32x4 acc[4][4] = {};
  const int nk = K >> 6;
  for (int kt = 0; kt < nk; ++kt) {
    __syncthreads();
    const short* pa = &A[(size_t)(bm + srow) * K + kt * 64 + scol];
    const short* pb = &BT[(size_t)(bn + srow) * K + kt * 64 + scol];
#pragma unroll
    for (int i = 0; i < 4; ++i) {
      gload_lds16(pa + (size_t)(i * 8) * K, &As[(wave * 32 + i * 8) * 64]);
      gload_lds16(pb + (size_t)(i * 8) * K, &Bs[(wave * 32 + i * 8) * 64]);
    }
    __syncthreads();
#pragma unroll
    for (int ks = 0; ks < 2; ++ks) {
      bf16x8 af[4], bfr[4];
#pragma unroll
      for (int mi = 0; mi < 4; ++mi)
        af[mi] = *reinterpret_cast<const bf16x8*>(&As[(64 * wr + 16 * mi + lr) * 64 + 8 * lg + 32 * ks]);
#pragma unroll
      for (int ni = 0; ni < 4; ++ni)
        bfr[ni] = *reinterpret_cast<const bf16x8*>(&Bs[(64 * wc + 16 * ni + lr) * 64 + 8 * lg + 32 * ks]);
#pragma unroll
      for (int mi = 0; mi < 4; ++mi)
#pragma unroll
        for (int ni = 0; ni < 4; ++ni)
          acc[mi][ni] = __builtin_amdgcn_mfma_f32_16x16x32_bf16(af[mi], bfr[ni], acc[mi][ni], 0, 0, 0);
    }
  }
  // epilogue: D layout col = lane&15, row = 4*(lane>>4)+r  [m89 verified]
#pragma unroll
  for (int mi = 0; mi < 4; ++mi) {
#pragma unroll
    for (int ni = 0; ni < 4; ++ni) {
#pragma unroll
      for (int r = 0; r < 4; ++r) {
        int row = bm + 64 * wr + 16 * mi + 4 * lg + r;
        int col = bn + 64 * wc + 16 * ni + lr;
        float v = acc[mi][ni][r] + bias[col];
        if (EPI == 0) {
          int b = row >> 11, s = row & (S_ - 1);
          int which = col >> 10, cm = col & (D_ - 1);
          int h = cm >> 6, dd = cm & 63;
          short bv = f2bf(v);
          size_t bh = (size_t)(b * H_ + h);
          if (which == 0)      Qh[(bh * S_ + s) * DEPTH_ + dd] = bv;
          else if (which == 1) Kh[(bh * S_ + s) * DEPTH_ + dd] = bv;
          else                 VTt[(bh * DEPTH_ + dd) * S_ + s] = bv;
        } else {
          Out[(size_t)row * N + col] = v;
        }
      }
    }
  }
}

// ---------- flash attention: 512 blocks = 32 bh x 16 pairs of q-tiles ----------
// Each block does q-tiles (31-p) then (p): exactly 33 kv-tile units -> perfect balance.
// Async-stage: next tile's K/V loaded to regs during compute, written to LDS after.
__global__ __launch_bounds__(256) void attn_kernel(
    const short* __restrict__ Qh, const short* __restrict__ Kh,
    const short* __restrict__ VTt, const float* __restrict__ mask,
    short* __restrict__ ctx) {
  constexpr int LK = 72;  // 64 + 8 pad
  constexpr float LOG2E = 1.44269504f;
  __shared__ short Ks[64 * LK];       // [kv][d]
  __shared__ short Vs[64 * LK];       // [d][kv]  (V^T)
  __shared__ short Ps[4][16 * LK];    // per-wave P strip [q][kv]
  const int bid = blockIdx.x;
  const int pr = bid & 15, bh = bid >> 4;
  const int b = bh >> 4, h = bh & 15;
  const short* Qp = Qh + (size_t)bh * S_ * DEPTH_;
  const short* Kp = Kh + (size_t)bh * S_ * DEPTH_;
  const short* Vp = VTt + (size_t)bh * DEPTH_ * S_;
  const int tid = threadIdx.x;
  const int wave = tid >> 6, lane = tid & 63;
  const int lr = lane & 15, lg = lane >> 4;
  const int srow = tid >> 3, scg = (tid & 7) * 8;  // staging: rows 0..31 (+32 for i=1)

  bf16x8 tk[2], tv[2];

  for (int half = 0; half < 2; ++half) {
    const int qt = half == 0 ? (31 - pr) : pr;
    const int q0 = qt * 64;
    const int nt = qt + 1;

    // Q fragments in registers (wave owns q rows [q0+16*wave, +16))
    bf16x8 qf[2];
    {
      int qrow = q0 + 16 * wave + lr;
      qf[0] = *reinterpret_cast<const bf16x8*>(&Qp[(size_t)qrow * DEPTH_ + 8 * lg]);
      qf[1] = *reinterpret_cast<const bf16x8*>(&Qp[(size_t)qrow * DEPTH_ + 32 + 8 * lg]);
    }
    float m_run[4], l_run[4];
    f32x4 acc_o[4] = {};
#pragma unroll
    for (int r = 0; r < 4; ++r) { m_run[r] = -1e30f; l_run[r] = 0.f; }

    // prologue: stage tile 0
#pragma unroll
    for (int i = 0; i < 2; ++i) {
      tk[i] = *reinterpret_cast<const bf16x8*>(&Kp[(size_t)(srow + 32 * i) * DEPTH_ + scg]);
      tv[i] = *reinterpret_cast<const bf16x8*>(&Vp[(size_t)(srow + 32 * i) * S_ + scg]);
    }
#pragma unroll
    for (int i = 0; i < 2; ++i) {
      *reinterpret_cast<bf16x8*>(&Ks[(srow + 32 * i) * LK + scg]) = tk[i];
      *reinterpret_cast<bf16x8*>(&Vs[(srow + 32 * i) * LK + scg]) = tv[i];
    }
    __syncthreads();

    for (int kt = 0; kt < nt; ++kt) {
      const int k0 = kt * 64;
      // issue next tile's loads (overlap with compute below)
      if (kt + 1 < nt) {
        const int kn = k0 + 64;
#pragma unroll
        for (int i = 0; i < 2; ++i) {
          tk[i] = *reinterpret_cast<const bf16x8*>(&Kp[(size_t)(kn + srow + 32 * i) * DEPTH_ + scg]);
          tv[i] = *reinterpret_cast<const bf16x8*>(&Vp[(size_t)(srow + 32 * i) * S_ + kn + scg]);
        }
      }

      // S = Q K^T : sc[f] holds q=4*lg+r (strip-local), kv=16*f+lr
      f32x4 sc[4];
#pragma unroll
      for (int f = 0; f < 4; ++f) { f32x4 z = {0.f, 0.f, 0.f, 0.f}; sc[f] = z; }
#pragma unroll
      for (int ks = 0; ks < 2; ++ks) {
#pragma unroll
        for (int f = 0; f < 4; ++f) {
          bf16x8 kf = *reinterpret_cast<const bf16x8*>(&Ks[(16 * f + lr) * LK + 8 * lg + 32 * ks]);
          sc[f] = __builtin_amdgcn_mfma_f32_16x16x32_bf16(qf[ks], kf, sc[f], 0, 0, 0);
        }
      }
      // scale (log2 domain) + additive mask + causal (diagonal tile only)
      constexpr float SC = 0.125f * LOG2E;
#pragma unroll
      for (int f = 0; f < 4; ++f) {
        float mv = mask[(size_t)b * S_ + k0 + 16 * f + lr] * LOG2E;
#pragma unroll
        for (int r = 0; r < 4; ++r) {
          float s = sc[f][r] * SC + mv;
          if (kt == nt - 1) {
            int qq = 16 * wave + 4 * lg + r;
            int kk = 16 * f + lr;
            if (kk > qq) s -= 2e9f;
          }
          sc[f][r] = s;
        }
      }
      // online softmax
#pragma unroll
      for (int r = 0; r < 4; ++r) {
        float m = fmaxf(fmaxf(sc[0][r], sc[1][r]), fmaxf(sc[2][r], sc[3][r]));
#pragma unroll
        for (int off = 1; off < 16; off <<= 1) m = fmaxf(m, __shfl_xor(m, off));
        float m_new = fmaxf(m_run[r], m);
        float corr = exp2f(m_run[r] - m_new);
        float su = 0.f;
#pragma unroll
        for (int f = 0; f < 4; ++f) {
          float p = exp2f(sc[f][r] - m_new);
          sc[f][r] = p;
          su += p;
        }
#pragma unroll
        for (int off = 1; off < 16; off <<= 1) su += __shfl_xor(su, off);
        l_run[r] = l_run[r] * corr + su;
        m_run[r] = m_new;
#pragma unroll
        for (int df = 0; df < 4; ++df) acc_o[df][r] *= corr;
      }
      // P -> wave-private LDS strip (same-wave write/read, no barrier)
#pragma unroll
      for (int f = 0; f < 4; ++f)
#pragma unroll
        for (int r = 0; r < 4; ++r)
          Ps[wave][(4 * lg + r) * LK + 16 * f + lr] = f2bf(sc[f][r]);
      // ctx += P V
#pragma unroll
      for (int ks = 0; ks < 2; ++ks) {
        bf16x8 ap = *reinterpret_cast<const bf16x8*>(&Ps[wave][lr * LK + 8 * lg + 32 * ks]);
#pragma unroll
        for (int df = 0; df < 4; ++df) {
          bf16x8 bv = *reinterpret_cast<const bf16x8*>(&Vs[(16 * df + lr) * LK + 8 * lg + 32 * ks]);
          acc_o[df] = __builtin_amdgcn_mfma_f32_16x16x32_bf16(ap, bv, acc_o[df], 0, 0, 0);
        }
      }
      __syncthreads();  // all waves done with LDS tile kt
      if (kt + 1 < nt) {
#pragma unroll
        for (int i = 0; i < 2; ++i) {
          *reinterpret_cast<bf16x8*>(&Ks[(srow + 32 * i) * LK + scg]) = tk[i];
          *reinterpret_cast<bf16x8*>(&Vs[(srow + 32 * i) * LK + scg]) = tv[i];
        }
        __syncthreads();  // LDS tile kt+1 visible
      }
    }
    // epilogue: ctx[b][q][h*64+d] bf16 (merged-head layout for out-proj)
#pragma unroll
    for (int df = 0; df < 4; ++df) {
#pragma unroll
      for (int r = 0; r < 4; ++r) {
        int q = q0 + 16 * wave + 4 * lg + r;
        int col = h * 64 + 16 * df + lr;
        float v = acc_o[df][r] / l_run[r];
        ctx[((size_t)b * S_ + q) * D_ + col] = f2bf(v);
      }
    }
    if (half == 0) __syncthreads();  // LDS safe to restage for second q-tile
  }
}

extern "C" void kernel_launch(void* const* d_in, const int* in_sizes, int n_in,
                              void* d_out, int out_size, void* d_ws, size_t ws_size,
                              hipStream_t stream) {
  const float* X    = (const float*)d_in[0];
  const float* mask = (const float*)d_in[1];
  const float* Wqkv = (const float*)d_in[2];
  const float* bqkv = (const float*)d_in[3];
  const float* Wout = (const float*)d_in[4];
  const float* bout = (const float*)d_in[5];
  float* Out = (float*)d_out;

  short* ws    = (short*)d_ws;
  short* Xb    = ws;                                   // 4096*1024 bf16
  short* WqkvT = Xb + (size_t)4096 * 1024;             // [3072][1024]
  short* WoutT = WqkvT + (size_t)3072 * 1024;          // [1024][1024]
  short* Qh    = WoutT + (size_t)1024 * 1024;          // [bh][s][64]
  short* Kh    = Qh + (size_t)B_ * H_ * S_ * DEPTH_;   // [bh][s][64]
  short* VTt   = Kh + (size_t)B_ * H_ * S_ * DEPTH_;   // [bh][64][s]
  short* ctx   = VTt + (size_t)B_ * H_ * S_ * DEPTH_;  // [b][s][1024]

  cast_kernel<<<4096, 256, 0, stream>>>(X, Xb, (4096 * 1024) / 4);
  transpose_cast_kernel<<<dim3(96, 32), dim3(32, 8), 0, stream>>>(Wqkv, WqkvT, 1024, 3072);
  transpose_cast_kernel<<<dim3(32, 32), dim3(32, 8), 0, stream>>>(Wout, WoutT, 1024, 1024);
  gemm_bt_kernel<0><<<dim3(24, 32), 256, 0, stream>>>(Xb, WqkvT, bqkv, Qh, Kh, VTt, nullptr,
                                                      4096, 3072, 1024);
  attn_kernel<<<512, 256, 0, stream>>>(Qh, Kh, VTt, mask, ctx);
  gemm_bt_kernel<1><<<dim3(8, 32), 256, 0, stream>>>(ctx, WoutT, bout, nullptr, nullptr, nullptr,
                                                     Out, 4096, 1024, 1024);
}